// Round 3
// baseline (85.767 us; speedup 1.0000x reference)
//
#include <hip/hip_runtime.h>
#include <math.h>

typedef float f32x4 __attribute__((ext_vector_type(4)));

struct R7 { float v[7]; };

__device__ __forceinline__ R7 se3_one(
    float tg0, float tg1, float tg2,
    float qw,  float qx,  float qy, float qz,
    float rx,  float ry,  float rz,
    float ox,  float oy,  float oz)
{
    // ---- so3 R, V (Rodrigues) ----
    float th2 = ox*ox + oy*oy + oz*oz;
    bool safe = th2 > 1e-12f;
    float ts = safe ? th2 : 1.0f;
    float theta = sqrtf(ts);
    float st = __sinf(theta);
    float ct = __cosf(theta);
    float inv3 = __fdividef(1.0f, ts * theta);        // 1/theta^3
    float A  = safe ? st * ts * inv3        : 1.0f;   // sin(t)/t
    float Bc = safe ? (1.0f - ct) * theta * inv3 : 0.0f;   // (1-cos)/t^2
    float Cc = safe ? (theta - st) * inv3   : (1.0f / 6.0f);

    // K2 = omega*omega^T - th2*I
    float xx = ox*ox - th2, yy = oy*oy - th2, zz = oz*oz - th2;
    float xy = ox*oy, xz = ox*oz, yz = oy*oz;

    float r00 = 1.0f + Bc*xx;
    float r01 = Bc*xy - A*oz;
    float r02 = Bc*xz + A*oy;
    float r10 = Bc*xy + A*oz;
    float r11 = 1.0f + Bc*yy;
    float r12 = Bc*yz - A*ox;
    float r20 = Bc*xz - A*oy;
    float r21 = Bc*yz + A*ox;
    float r22 = 1.0f + Bc*zz;

    float v00 = 1.0f + Cc*xx;
    float v01 = Cc*xy - Bc*oz;
    float v02 = Cc*xz + Bc*oy;
    float v10 = Cc*xy + Bc*oz;
    float v11 = 1.0f + Cc*yy;
    float v12 = Cc*yz - Bc*ox;
    float v20 = Cc*xz - Bc*oy;
    float v21 = Cc*yz + Bc*ox;
    float v22 = 1.0f + Cc*zz;

    float txi0 = v00*rx + v01*ry + v02*rz;
    float txi1 = v10*rx + v11*ry + v12*rz;
    float txi2 = v20*rx + v21*ry + v22*rz;

    // Rg = quat -> matrix
    float g00 = 1.0f - 2.0f*(qy*qy + qz*qz);
    float g01 = 2.0f*(qx*qy - qz*qw);
    float g02 = 2.0f*(qx*qz + qy*qw);
    float g10 = 2.0f*(qx*qy + qz*qw);
    float g11 = 1.0f - 2.0f*(qx*qx + qz*qz);
    float g12 = 2.0f*(qy*qz - qx*qw);
    float g20 = 2.0f*(qx*qz - qy*qw);
    float g21 = 2.0f*(qy*qz + qx*qw);
    float g22 = 1.0f - 2.0f*(qx*qx + qy*qy);

    // M = R @ Rg
    float m00 = r00*g00 + r01*g10 + r02*g20;
    float m01 = r00*g01 + r01*g11 + r02*g21;
    float m02 = r00*g02 + r01*g12 + r02*g22;
    float m10 = r10*g00 + r11*g10 + r12*g20;
    float m11 = r10*g01 + r11*g11 + r12*g21;
    float m12 = r10*g02 + r11*g12 + r12*g22;
    float m20 = r20*g00 + r21*g10 + r22*g20;
    float m21 = r20*g01 + r21*g11 + r22*g21;
    float m22 = r20*g02 + r21*g12 + r22*g22;

    // t = R @ tg + t_xi
    float t0 = r00*tg0 + r01*tg1 + r02*tg2 + txi0;
    float t1 = r10*tg0 + r11*tg1 + r12*tg2 + txi1;
    float t2 = r20*tg0 + r21*tg1 + r22*tg2 + txi2;

    // ---- matrix -> quaternion (Shepperd, reference branch structure) ----
    bool c_m22  = m22 < 0.0f;
    bool c_0g1  = m00 > m11;
    bool c_0ln1 = m00 < -m11;
    float t, qa, qb, qc, qd;
    if (c_m22) {
        if (c_0g1) {
            t = 1.0f + m00 - m11 - m22;
            qa = m21 - m12; qb = t;         qc = m01 + m10; qd = m20 + m02;
        } else {
            t = 1.0f - m00 + m11 - m22;
            qa = m02 - m20; qb = m01 + m10; qc = t;         qd = m12 + m21;
        }
    } else {
        if (c_0ln1) {
            t = 1.0f - m00 - m11 + m22;
            qa = m10 - m01; qb = m20 + m02; qc = m12 + m21; qd = t;
        } else {
            t = 1.0f + m00 + m11 + m22;
            qa = t;         qb = m21 - m12; qc = m02 - m20; qd = m10 - m01;
        }
    }
    float s = 0.5f * rsqrtf(t);
    qa *= s; qb *= s; qc *= s; qd *= s;
    if (qa < 0.0f) { qa = -qa; qb = -qb; qc = -qc; qd = -qd; }

    R7 r;
    r.v[0] = t0; r.v[1] = t1; r.v[2] = t2;
    r.v[3] = qa; r.v[4] = qb; r.v[5] = qc; r.v[6] = qd;
    return r;
}

__global__ __launch_bounds__(256) void se3comp_kernel(
    const f32x4* __restrict__ Tg4, const f32x4* __restrict__ xi4,
    f32x4* __restrict__ out4, int n)
{
    const int j = blockIdx.x * blockDim.x + threadIdx.x;
    const int base = j * 4;
    if (base >= n) return;

    if (base + 3 < n) {
        // ---- fast path: 4 elements, all-float4 I/O ----
        float tgf[28], xif[24];
        #pragma unroll
        for (int k = 0; k < 7; ++k) {
            f32x4 v = Tg4[(size_t)j * 7 + k];
            tgf[k*4+0] = v.x; tgf[k*4+1] = v.y; tgf[k*4+2] = v.z; tgf[k*4+3] = v.w;
        }
        #pragma unroll
        for (int k = 0; k < 6; ++k) {
            f32x4 v = xi4[(size_t)j * 6 + k];
            xif[k*4+0] = v.x; xif[k*4+1] = v.y; xif[k*4+2] = v.z; xif[k*4+3] = v.w;
        }

        float of[28];
        #pragma unroll
        for (int e = 0; e < 4; ++e) {
            R7 r = se3_one(tgf[e*7+0], tgf[e*7+1], tgf[e*7+2],
                           tgf[e*7+3], tgf[e*7+4], tgf[e*7+5], tgf[e*7+6],
                           xif[e*6+0], xif[e*6+1], xif[e*6+2],
                           xif[e*6+3], xif[e*6+4], xif[e*6+5]);
            #pragma unroll
            for (int f = 0; f < 7; ++f) of[e*7+f] = r.v[f];
        }

        #pragma unroll
        for (int k = 0; k < 7; ++k) {
            f32x4 v;
            v.x = of[k*4+0]; v.y = of[k*4+1]; v.z = of[k*4+2]; v.w = of[k*4+3];
            __builtin_nontemporal_store(v, &out4[(size_t)j * 7 + k]);
        }
    } else {
        // ---- scalar tail ----
        const float* Tgf = reinterpret_cast<const float*>(Tg4);
        const float* xif = reinterpret_cast<const float*>(xi4);
        float* outf = reinterpret_cast<float*>(out4);
        for (int e = base; e < n; ++e) {
            const float* g = Tgf + (size_t)e * 7;
            const float* x = xif + (size_t)e * 6;
            R7 r = se3_one(g[0], g[1], g[2], g[3], g[4], g[5], g[6],
                           x[0], x[1], x[2], x[3], x[4], x[5]);
            float* o = outf + (size_t)e * 7;
            for (int f = 0; f < 7; ++f) o[f] = r.v[f];
        }
    }
}

extern "C" void kernel_launch(void* const* d_in, const int* in_sizes, int n_in,
                              void* d_out, int out_size, void* d_ws, size_t ws_size,
                              hipStream_t stream) {
    const f32x4* Tg = (const f32x4*)d_in[0];
    const f32x4* xi = (const f32x4*)d_in[1];
    f32x4* out = (f32x4*)d_out;
    int n = in_sizes[0] / 7;                 // B
    int nThreads = (n + 3) / 4;
    int grid = (nThreads + 255) / 256;
    hipLaunchKernelGGL(se3comp_kernel, dim3(grid), dim3(256), 0, stream,
                       Tg, xi, out, n);
}

// Round 4
// 28.601 us; speedup vs baseline: 2.9987x; 2.9987x over previous
//
#include <hip/hip_runtime.h>
#include <math.h>

__global__ __launch_bounds__(256) void se3comp_kernel(
    const float* __restrict__ Tg, const float* __restrict__ xi,
    float* __restrict__ out, int n)
{
    int i = blockIdx.x * blockDim.x + threadIdx.x;
    if (i >= n) return;

    // ---- load xi: rho (3), omega (3), stride 6 floats -> 3x float2 ----
    const float2* x2 = reinterpret_cast<const float2*>(xi) + (size_t)i * 3;
    float2 a0 = x2[0], a1 = x2[1], a2 = x2[2];
    float rx = a0.x, ry = a0.y, rz = a1.x;
    float ox = a1.y, oy = a2.x, oz = a2.y;

    // ---- so3 R, V (Rodrigues) with HW transcendentals ----
    float th2 = ox*ox + oy*oy + oz*oz;
    bool safe = th2 > 1e-12f;
    float ts = safe ? th2 : 1.0f;
    float theta = sqrtf(ts);
    float st = __sinf(theta);
    float ct = __cosf(theta);
    float inv3 = __fdividef(1.0f, ts * theta);             // 1/theta^3
    float A  = safe ? st * ts * inv3             : 1.0f;   // sin(t)/t
    float Bc = safe ? (1.0f - ct) * theta * inv3 : 0.0f;   // (1-cos)/t^2
    float Cc = safe ? (theta - st) * inv3        : (1.0f / 6.0f);

    // K2 = omega*omega^T - th2*I  (matches matmul(K,K))
    float xx = ox*ox - th2, yy = oy*oy - th2, zz = oz*oz - th2;
    float xy = ox*oy, xz = ox*oz, yz = oy*oz;

    float r00 = 1.0f + Bc*xx;
    float r01 = Bc*xy - A*oz;
    float r02 = Bc*xz + A*oy;
    float r10 = Bc*xy + A*oz;
    float r11 = 1.0f + Bc*yy;
    float r12 = Bc*yz - A*ox;
    float r20 = Bc*xz - A*oy;
    float r21 = Bc*yz + A*ox;
    float r22 = 1.0f + Bc*zz;

    float v00 = 1.0f + Cc*xx;
    float v01 = Cc*xy - Bc*oz;
    float v02 = Cc*xz + Bc*oy;
    float v10 = Cc*xy + Bc*oz;
    float v11 = 1.0f + Cc*yy;
    float v12 = Cc*yz - Bc*ox;
    float v20 = Cc*xz - Bc*oy;
    float v21 = Cc*yz + Bc*ox;
    float v22 = 1.0f + Cc*zz;

    // t_xi = V @ rho
    float txi0 = v00*rx + v01*ry + v02*rz;
    float txi1 = v10*rx + v11*ry + v12*rz;
    float txi2 = v20*rx + v21*ry + v22*rz;

    // ---- load Tg: trans (3), quat wxyz (4), stride 7 floats ----
    const float* g = Tg + (size_t)i * 7;
    float tg0 = g[0], tg1 = g[1], tg2 = g[2];
    float qw = g[3], qx = g[4], qy = g[5], qz = g[6];

    // Rg = quat -> matrix
    float g00 = 1.0f - 2.0f*(qy*qy + qz*qz);
    float g01 = 2.0f*(qx*qy - qz*qw);
    float g02 = 2.0f*(qx*qz + qy*qw);
    float g10 = 2.0f*(qx*qy + qz*qw);
    float g11 = 1.0f - 2.0f*(qx*qx + qz*qz);
    float g12 = 2.0f*(qy*qz - qx*qw);
    float g20 = 2.0f*(qx*qz - qy*qw);
    float g21 = 2.0f*(qy*qz + qx*qw);
    float g22 = 1.0f - 2.0f*(qx*qx + qy*qy);

    // M = R @ Rg
    float m00 = r00*g00 + r01*g10 + r02*g20;
    float m01 = r00*g01 + r01*g11 + r02*g21;
    float m02 = r00*g02 + r01*g12 + r02*g22;
    float m10 = r10*g00 + r11*g10 + r12*g20;
    float m11 = r10*g01 + r11*g11 + r12*g21;
    float m12 = r10*g02 + r11*g12 + r12*g22;
    float m20 = r20*g00 + r21*g10 + r22*g20;
    float m21 = r20*g01 + r21*g11 + r22*g21;
    float m22 = r20*g02 + r21*g12 + r22*g22;

    // t = R @ tg + t_xi
    float t0 = r00*tg0 + r01*tg1 + r02*tg2 + txi0;
    float t1 = r10*tg0 + r11*tg1 + r12*tg2 + txi1;
    float t2 = r20*tg0 + r21*tg1 + r22*tg2 + txi2;

    // ---- matrix -> quaternion (Shepperd, reference branch structure) ----
    bool c_m22  = m22 < 0.0f;
    bool c_0g1  = m00 > m11;
    bool c_0ln1 = m00 < -m11;
    float t, qa, qb, qc, qd;
    if (c_m22) {
        if (c_0g1) {
            t = 1.0f + m00 - m11 - m22;
            qa = m21 - m12; qb = t;         qc = m01 + m10; qd = m20 + m02;
        } else {
            t = 1.0f - m00 + m11 - m22;
            qa = m02 - m20; qb = m01 + m10; qc = t;         qd = m12 + m21;
        }
    } else {
        if (c_0ln1) {
            t = 1.0f - m00 - m11 + m22;
            qa = m10 - m01; qb = m20 + m02; qc = m12 + m21; qd = t;
        } else {
            t = 1.0f + m00 + m11 + m22;
            qa = t;         qb = m21 - m12; qc = m02 - m20; qd = m10 - m01;
        }
    }
    float s = 0.5f * rsqrtf(t);
    qa *= s; qb *= s; qc *= s; qd *= s;
    if (qa < 0.0f) { qa = -qa; qb = -qb; qc = -qc; qd = -qd; }

    // ---- store r7 = [t, q], stride 7 floats (plain stores: L2 merges) ----
    float* o = out + (size_t)i * 7;
    o[0] = t0; o[1] = t1; o[2] = t2;
    o[3] = qa; o[4] = qb; o[5] = qc; o[6] = qd;
}

extern "C" void kernel_launch(void* const* d_in, const int* in_sizes, int n_in,
                              void* d_out, int out_size, void* d_ws, size_t ws_size,
                              hipStream_t stream) {
    const float* Tg = (const float*)d_in[0];
    const float* xi = (const float*)d_in[1];
    float* out = (float*)d_out;
    int n = in_sizes[0] / 7;   // B
    const int block = 256;
    int grid = (n + block - 1) / block;
    hipLaunchKernelGGL(se3comp_kernel, dim3(grid), dim3(block), 0, stream,
                       Tg, xi, out, n);
}